// Round 11
// baseline (2219.878 us; speedup 1.0000x reference)
//
#include <hip/hip_runtime.h>

#define TT 1024
#define LOG2E 1.44269504088896340736f

typedef __attribute__((ext_vector_type(8))) short s16x8;
typedef __attribute__((ext_vector_type(4))) float f32x4;
typedef __attribute__((ext_vector_type(4))) unsigned int u32x4;
typedef __attribute__((ext_vector_type(2))) unsigned int u32x2;

__device__ __forceinline__ float ex2(float x){ return __builtin_amdgcn_exp2f(x); }
__device__ __forceinline__ float rcp_(float x){ return __builtin_amdgcn_rcpf(x); }
__device__ __forceinline__ float sigm(float x){ return rcp_(1.f + ex2(-LOG2E*x)); }
__device__ __forceinline__ float tanh_(float x){
  float t = ex2(2.f*LOG2E*x);
  return 1.f - 2.f*rcp_(t + 1.f);
}
__device__ __forceinline__ unsigned short f2bf(float f){
  unsigned int u = __float_as_uint(f);
  u += 0x7fffu + ((u>>16)&1u);
  return (unsigned short)(u>>16);
}
__device__ __forceinline__ float bflo(unsigned int u){ return __uint_as_float(u << 16); }
__device__ __forceinline__ float bfhi(unsigned int u){ return __uint_as_float(u & 0xffff0000u); }

// ---------------------------------------------------------------------------
// Phase 0a: pack weights into MFMA B-fragment layout, bf16. (round-0 proven)
// Wpk layout: [d(2)][tau(66)][s(9)][lane(64)][8 bf16]
// ---------------------------------------------------------------------------
__global__ __launch_bounds__(256) void pack_weights(
    const float* __restrict__ WhhF, const float* __restrict__ WihF,
    const float* __restrict__ WhhB, const float* __restrict__ WihB,
    const float* __restrict__ outW, unsigned short* __restrict__ Wpk)
{
  int gid = blockIdx.x*256 + threadIdx.x;
  const int TOT = 2*66*9*64;
  if (gid >= TOT) return;
  int l   = gid & 63;
  int s   = (gid>>6) % 9;
  int tau = ((gid>>6)/9) % 66;
  int d   = gid / (66*9*64);
  const float* Whh = d ? WhhB : WhhF;
  const float* Wih = d ? WihB : WihF;
  int kb = s*32 + (l>>4)*8;
  int cr = l & 15;
  unsigned short v[8];
  #pragma unroll
  for (int j=0;j<8;j++){
    int k = kb + j;
    float val = 0.f;
    if (tau < 64){
      int col = 256*(tau&3) + 16*(tau>>2) + cr;
      if (k < 256)      val = Whh[col*256 + k];
      else if (k < 275) val = Wih[col*19 + (k-256)];
    } else {
      int col = 16*(tau-64) + cr;
      if (k < 256)      val = outW[col*512 + d*256 + k];
    }
    v[j] = f2bf(val);
  }
  u32x4 pk;
  pk[0] = (unsigned)v[0] | ((unsigned)v[1]<<16);
  pk[1] = (unsigned)v[2] | ((unsigned)v[3]<<16);
  pk[2] = (unsigned)v[4] | ((unsigned)v[5]<<16);
  pk[3] = (unsigned)v[6] | ((unsigned)v[7]<<16);
  *(u32x4*)&Wpk[(size_t)gid*8] = pk;
}

// ---------------------------------------------------------------------------
// Phase 0b: precompute the slice-8 A-fragment (x + time embed). (r6 proven)
// ---------------------------------------------------------------------------
__global__ __launch_bounds__(64) void pack_x(
    const float* __restrict__ loc, const float* __restrict__ tds,
    const float* __restrict__ timeW, const float* __restrict__ timeB,
    unsigned short* __restrict__ Xpk)
{
  int bid = blockIdx.x;            // grp*TT + t
  int t   = bid & (TT-1);
  int grp = bid >> 10;
  int l = threadIdx.x;
  int b = l & 15;
  int khi = l >> 4;
  unsigned short v[8];
  #pragma unroll
  for (int j=0;j<8;j++){
    int k = khi*8 + j;
    float val = 0.f;
    if (k < 16){
      val = loc[(((size_t)(grp*16 + b))*TT + t)*16 + k];
    } else if (k < 19){
      int jj = k - 16;
      const float* pt = &tds[(((size_t)(grp*16 + b))*TT + t)*8];
      float td = timeB[jj];
      #pragma unroll
      for (int dd=0; dd<4; dd++) td += pt[dd]*timeW[jj*8+dd] + pt[4+dd]*timeW[jj*8+4+dd];
      val = td;
    }
    v[j] = f2bf(val);
  }
  u32x4 pk;
  pk[0] = (unsigned)v[0] | ((unsigned)v[1]<<16);
  pk[1] = (unsigned)v[2] | ((unsigned)v[3]<<16);
  pk[2] = (unsigned)v[4] | ((unsigned)v[5]<<16);
  pk[3] = (unsigned)v[6] | ((unsigned)v[7]<<16);
  *(u32x4*)&Xpk[(size_t)bid*512 + l*8] = pk;
}

__global__ void zero_flags(int* __restrict__ f){ f[threadIdx.x] = 0; }

// ---------------------------------------------------------------------------
// do_own<H>: 5 MFMA slices (own half h + x). do_par<H>: 4 partner slices.
// Compile-time weight indices. Summation order identical to round-8/9.
// ---------------------------------------------------------------------------
template<int H>
__device__ __forceinline__ void do_own(
    const s16x8 (&wgt)[9][4],
    s16x8 a0, s16x8 a1, s16x8 a2, s16x8 a3, s16x8 ax,
    f32x4 (&acc)[4])
{
  constexpr int O = H ? 4 : 0;
  f32x4 zz = {0.f,0.f,0.f,0.f};
  #pragma unroll
  for (int g=0;g<4;g++) acc[g] = __builtin_amdgcn_mfma_f32_16x16x32_bf16(a0, wgt[O+0][g], zz,     0,0,0);
  #pragma unroll
  for (int g=0;g<4;g++) acc[g] = __builtin_amdgcn_mfma_f32_16x16x32_bf16(a1, wgt[O+1][g], acc[g], 0,0,0);
  #pragma unroll
  for (int g=0;g<4;g++) acc[g] = __builtin_amdgcn_mfma_f32_16x16x32_bf16(a2, wgt[O+2][g], acc[g], 0,0,0);
  #pragma unroll
  for (int g=0;g<4;g++) acc[g] = __builtin_amdgcn_mfma_f32_16x16x32_bf16(a3, wgt[O+3][g], acc[g], 0,0,0);
  #pragma unroll
  for (int g=0;g<4;g++) acc[g] = __builtin_amdgcn_mfma_f32_16x16x32_bf16(ax, wgt[8][g],   acc[g], 0,0,0);
}

template<int H>
__device__ __forceinline__ void do_par(
    const s16x8 (&wgt)[9][4],
    s16x8 p0, s16x8 p1, s16x8 p2, s16x8 p3,
    f32x4 (&acc)[4])
{
  constexpr int P = H ? 0 : 4;
  #pragma unroll
  for (int g=0;g<4;g++) acc[g] = __builtin_amdgcn_mfma_f32_16x16x32_bf16(p0, wgt[P+0][g], acc[g], 0,0,0);
  #pragma unroll
  for (int g=0;g<4;g++) acc[g] = __builtin_amdgcn_mfma_f32_16x16x32_bf16(p1, wgt[P+1][g], acc[g], 0,0,0);
  #pragma unroll
  for (int g=0;g<4;g++) acc[g] = __builtin_amdgcn_mfma_f32_16x16x32_bf16(p2, wgt[P+2][g], acc[g], 0,0,0);
  #pragma unroll
  for (int g=0;g<4;g++) acc[g] = __builtin_amdgcn_mfma_f32_16x16x32_bf16(p3, wgt[P+3][g], acc[g], 0,0,0);
}

// ---------------------------------------------------------------------------
// Phase 1 (primary): hidden-split LSTM. 32 blocks x 512 threads (8 waves).
// SYNC PROTOCOL = round-9 verbatim (verified pass, 2071us): full
// __syncthreads drain + tid0 sc1 flag + s_sleep spin + r9 load/wait order.
// (r10's per-wave-flag + lgkm-only-barrier bundle failed the container;
// reverted per pre-commitment.)
// Two protocol-neutral latency trims vs r9:
//  (1) wave-2 next-x prefetch issued right after the tied partner wait
//      (3-deep shift register xr0/xr1/xr2) instead of last in the epilogue:
//      its ~300-500cy flight hides under do_par+epilogue, not the barrier.
//  (2) epilogue reordered: compute all 4 h, issue the 4 sc1 global stores
//      FIRST, then the 4 LDS stores -> last store's LLC ack starts earlier.
// ---------------------------------------------------------------------------
__global__ __launch_bounds__(512, 2) __attribute__((amdgpu_waves_per_eu(2, 2)))
void lstm_split(
    const int* __restrict__ dlen,
    const float* __restrict__ bF, const float* __restrict__ bB,
    const unsigned short* __restrict__ Wpk,
    const unsigned short* __restrict__ Xpk,
    unsigned short* __restrict__ h_all,
    int* __restrict__ flags)
{
  __shared__ alignas(16) unsigned short Albuf[2][4608];
  int tid = threadIdx.x;
  int w = tid >> 6, l = tid & 63;          // w in 0..7
  int bid = blockIdx.x;
  int d = bid >> 4, grp = (bid >> 1) & 7, half = bid & 1;
  int quad = l >> 4, cr = l & 15;
  int W = half*8 + w;                      // absolute unit-block 0..15

  { unsigned int* az = (unsigned int*)&Albuf[0][0];
    for (int i = tid; i < 4608; i += 512) az[i] = 0u; }

  int lens[4];
  #pragma unroll
  for (int i=0;i<4;i++) lens[i] = dlen[grp*16 + quad*4 + i];
  int maxlen = dlen[grp*16];               // lengths sorted descending

  const float* bias = d ? bB : bF;
  float biasr[4];
  #pragma unroll
  for (int g=0;g<4;g++) biasr[g] = bias[256*g + 16*W + cr];

  const s16x8* BP = (const s16x8*)Wpk;
  int btile = (d*66 + 4*W)*9*64;

  // ALL weights resident: 9 slices x 4 gates, loaded once, pinned.
  s16x8 wgt[9][4];
  #pragma unroll
  for (int s=0;s<9;s++){
    #pragma unroll
    for (int g=0;g<4;g++){
      wgt[s][g] = BP[btile + (g*9+s)*64 + l];
      asm volatile("" : "+v"(wgt[s][g]));
    }
  }

  const unsigned short* Xg = Xpk + (size_t)grp*TT*512;
  int pairbase = (d*8 + grp)*2;
  int* myf = &flags[pairbase + half];
  int* prf = &flags[pairbase + (half^1)];

  float c[4], h[4];
  #pragma unroll
  for (int i=0;i<4;i++){ c[i]=0.f; h[i]=0.f; }

  __syncthreads();   // zero done

  // x shift-register prologue (wave 2), r6-proven
  u32x4 xr0 = {0,0,0,0}, xr1 = {0,0,0,0};
  if (w == 2){
    int tt0 = d ? (maxlen-1) : 0;
    int tt1 = d ? (maxlen-2) : 1;
    int tt2 = d ? (maxlen-3) : 2;
    tt1 = tt1 < 0 ? 0 : (tt1 > TT-1 ? TT-1 : tt1);
    tt2 = tt2 < 0 ? 0 : (tt2 > TT-1 ? TT-1 : tt2);
    u32x4 x0 = *(const u32x4*)&Xg[(size_t)tt0*512 + l*8];
    xr0 = *(const u32x4*)&Xg[(size_t)tt1*512 + l*8];
    xr1 = *(const u32x4*)&Xg[(size_t)tt2*512 + l*8];
    *(u32x4*)&Albuf[0][4096 + l*8] = x0;
  }
  __syncthreads();

  int ob = half ? 4 : 0;                   // own slice base
  int pb = half ? 0 : 4;                   // partner slice base

  int p = 0;
  for (int vs = 0; vs < maxlen; vs++){
    int tg = d ? (maxlen-1-vs) : vs;
    const s16x8* ap = (const s16x8*)&Albuf[p][0];

    // own A-frags (LDS)
    s16x8 a0 = ap[(ob+0)*64 + l];
    s16x8 a1 = ap[(ob+1)*64 + l];
    s16x8 a2 = ap[(ob+2)*64 + l];
    s16x8 a3 = ap[(ob+3)*64 + l];
    s16x8 ax = ap[512 + l];                // slice 8 (x)

    // spin (usually one LLC read), then ISSUE partner sc1 loads (no wait yet)
    s16x8 p0 = {0,0,0,0,0,0,0,0};
    s16x8 p1 = p0, p2 = p0, p3 = p0;
    if (vs > 0){
      while (__hip_atomic_load(prf, __ATOMIC_RELAXED, __HIP_MEMORY_SCOPE_SYSTEM) < vs)
        __builtin_amdgcn_s_sleep(1);
      int tprev = d ? (tg+1) : (tg-1);
      const unsigned short* pt = h_all + ((size_t)((d*8+grp)*TT + tprev))*4096;
      asm volatile("global_load_dwordx4 %0, %1, off sc0 sc1"
                   : "=v"(p0) : "v"(&pt[(pb+0)*512 + l*8]) : "memory");
      asm volatile("global_load_dwordx4 %0, %1, off sc0 sc1"
                   : "=v"(p1) : "v"(&pt[(pb+1)*512 + l*8]) : "memory");
      asm volatile("global_load_dwordx4 %0, %1, off sc0 sc1"
                   : "=v"(p2) : "v"(&pt[(pb+2)*512 + l*8]) : "memory");
      asm volatile("global_load_dwordx4 %0, %1, off sc0 sc1"
                   : "=v"(p3) : "v"(&pt[(pb+3)*512 + l*8]) : "memory");
    }

    f32x4 acc[4];
    if (half == 0) do_own<0>(wgt, a0,a1,a2,a3,ax, acc);
    else           do_own<1>(wgt, a0,a1,a2,a3,ax, acc);

    // wait the partner loads; tie p0..p3 so MFMAs can't hoist past (rule #18)
    asm volatile("s_waitcnt vmcnt(0)"
                 : "+v"(p0), "+v"(p1), "+v"(p2), "+v"(p3) :: "memory");
    __builtin_amdgcn_sched_barrier(0);

    // trim (1): issue wave-2's next-x load NOW so it flies under
    // do_par + the epilogue instead of inside the barrier drain.
    u32x4 xr2 = {0,0,0,0};
    if (w == 2){
      int t3 = d ? (tg-3) : (tg+3);
      t3 = t3 < 0 ? 0 : (t3 > TT-1 ? TT-1 : t3);
      xr2 = *(const u32x4*)&Xg[(size_t)t3*512 + l*8];
    }

    if (half == 0) do_par<0>(wgt, p0,p1,p2,p3, acc);
    else           do_par<1>(wgt, p0,p1,p2,p3, acc);

    int wb = p ^ 1;
    int kh = 16*W + cr;
    int s_ = kh >> 5, q_ = (kh>>3)&3, ko = kh & 7;
    unsigned short* hp = h_all + ((size_t)((d*8+grp)*TT + tg))*4096 + s_*512 + q_*128 + ko;
    // trim (2): compute all 4 h first, global sc1 stores first, LDS after.
    unsigned short hb[4];
    #pragma unroll
    for (int i=0;i<4;i++){
      float ig = acc[0][i] + biasr[0];
      float fg = acc[1][i] + biasr[1];
      float gg = acc[2][i] + biasr[2];
      float og = acc[3][i] + biasr[3];
      float cn = sigm(fg)*c[i] + sigm(ig)*tanh_(gg);
      float hn = sigm(og)*tanh_(cn);
      bool mk = (tg < lens[i]);
      c[i] = mk ? cn : c[i];
      h[i] = mk ? hn : h[i];
      hb[i] = f2bf(h[i]);
    }
    #pragma unroll
    for (int i=0;i<4;i++)
      __hip_atomic_store(&hp[(quad*4+i)*8], hb[i], __ATOMIC_RELAXED,
                         __HIP_MEMORY_SCOPE_SYSTEM);
    #pragma unroll
    for (int i=0;i<4;i++)
      Albuf[wb][s_*512 + q_*128 + (quad*4+i)*8 + ko] = hb[i];
    // x(t_next) from the 3-deep shift register (xr2 issued above)
    if (w == 2){
      *(u32x4*)&Albuf[wb][4096 + l*8] = xr0;
      xr0 = xr1;
      xr1 = xr2;
    }
    __syncthreads();   // vmcnt(0) per wave: all sc1 h stores are LLC-visible
    if (tid == 0){
      int fv = vs + 1;
      asm volatile("global_store_dword %0, %1, off sc0 sc1"
                   :: "v"(myf), "v"(fv) : "memory");
    }
    p ^= 1;
  }
}

// ---------------------------------------------------------------------------
// Phase 1 (fallback, r7-verified): 16-block persistent LSTM, template HM.
// ---------------------------------------------------------------------------
template<int HM>
__global__ __launch_bounds__(1024) void lstm_kernel(
    const int* __restrict__ dlen,
    const float* __restrict__ bF, const float* __restrict__ bB,
    const unsigned short* __restrict__ Wpk,
    const unsigned short* __restrict__ Xpk,
    unsigned short* __restrict__ y_ws,
    unsigned short* __restrict__ h_all)
{
  __shared__ alignas(16) unsigned short Albuf[2][4608];
  int tid = threadIdx.x;
  int w = tid >> 6, l = tid & 63;
  int bid = blockIdx.x;
  int d = bid >> 3, grp = bid & 7;
  int quad = l >> 4, cr = l & 15;

  { unsigned int* az = (unsigned int*)&Albuf[0][0];
    for (int i = tid; i < 4608; i += 1024) az[i] = 0u; }

  int lens[4];
  #pragma unroll
  for (int i=0;i<4;i++) lens[i] = dlen[grp*16 + quad*4 + i];
  int maxlen = dlen[grp*16];

  const float* bias = d ? bB : bF;
  float biasr[4];
  #pragma unroll
  for (int g=0;g<4;g++) biasr[g] = bias[256*g + 16*w + cr];

  const s16x8* BP = (const s16x8*)Wpk;
  int btile  = (d*66 + 4*w)*9*64;
  int bytile = (d*66 + 64 + w)*9*64;
  bool has_y = (HM == 0) && (w < 2);

  const unsigned short* Xg = Xpk + (size_t)grp*TT*512;

  float c[4], h[4];
  #pragma unroll
  for (int i=0;i<4;i++){ c[i]=0.f; h[i]=0.f; }

  __syncthreads();

  u32x4 xr0 = {0,0,0,0}, xr1 = {0,0,0,0};
  if (w == 2){
    int tt0 = d ? (maxlen-1) : 0;
    int tt1 = d ? (maxlen-2) : 1;
    int tt2 = d ? (maxlen-3) : 2;
    tt1 = tt1 < 0 ? 0 : (tt1 > TT-1 ? TT-1 : tt1);
    tt2 = tt2 < 0 ? 0 : (tt2 > TT-1 ? TT-1 : tt2);
    u32x4 x0 = *(const u32x4*)&Xg[(size_t)tt0*512 + l*8];
    xr0 = *(const u32x4*)&Xg[(size_t)tt1*512 + l*8];
    xr1 = *(const u32x4*)&Xg[(size_t)tt2*512 + l*8];
    *(u32x4*)&Albuf[0][4096 + l*8] = x0;
  }
  __syncthreads();

  int p = 0;
  for (int vs = 0; vs <= maxlen; vs++){
    int tg = d ? (maxlen-1-vs) : vs;
    int ty = d ? (maxlen-vs)   : (vs-1);
    bool do_g = (vs < maxlen);

    const s16x8* ap = (const s16x8*)&Albuf[p][0];

    if (has_y && vs > 0){
      f32x4 yacc;
      s16x8 ya  = ap[l], yan;
      s16x8 yb0 = BP[bytile + l], ybn;
      #pragma unroll
      for (int s=0;s<9;s++){
        if (s < 8){
          yan = ap[(s+1)*64 + l];
          ybn = BP[bytile + (s+1)*64 + l];
        }
        if (s == 0){
          f32x4 zz = {0.f,0.f,0.f,0.f};
          yacc = __builtin_amdgcn_mfma_f32_16x16x32_bf16(ya, yb0, zz, 0,0,0);
        } else {
          yacc = __builtin_amdgcn_mfma_f32_16x16x32_bf16(ya, yb0, yacc, 0,0,0);
        }
        ya = yan; yb0 = ybn;
      }
      size_t ybase = ((((size_t)d*8 + grp)*TT + (size_t)ty)*16)*32;
      #pragma unroll
      for (int i=0;i<4;i++)
        y_ws[ybase + (size_t)(quad*4+i)*32 + 16*w + cr] = f2bf(yacc[i]);
    }

    if (do_g){
      f32x4 acc[4];
      s16x8 bb[2][4];
      #pragma unroll
      for (int g=0;g<4;g++) bb[0][g] = BP[btile + (g*9)*64 + l];
      #pragma unroll
      for (int g=0;g<4;g++) bb[1][g] = BP[btile + (g*9+1)*64 + l];
      s16x8 a_c = ap[l], a_n;
      #pragma unroll
      for (int s=0;s<9;s++){
        const int cu = s & 1;
        if (s < 8) a_n = ap[(s+1)*64 + l];
        #pragma unroll
        for (int g=0;g<4;g++){
          if (s == 0){
            f32x4 zz = {0.f,0.f,0.f,0.f};
            acc[g] = __builtin_amdgcn_mfma_f32_16x16x32_bf16(a_c, bb[cu][g], zz, 0,0,0);
          } else {
            acc[g] = __builtin_amdgcn_mfma_f32_16x16x32_bf16(a_c, bb[cu][g], acc[g], 0,0,0);
          }
        }
        if (s < 7){
          #pragma unroll
          for (int g=0;g<4;g++)
            bb[cu][g] = BP[btile + (g*9 + s+2)*64 + l];
        }
        a_c = a_n;
      }

      int wb = p ^ 1;
      int kh = 16*w + cr;
      int s_ = kh >> 5, q_ = (kh>>3)&3, ko = kh & 7;
      unsigned short* hp = (HM == 1)
        ? (h_all + ((size_t)((d*8+grp)*TT + tg))*4096 + s_*512 + q_*128 + ko)
        : nullptr;
      #pragma unroll
      for (int i=0;i<4;i++){
        float ig = acc[0][i] + biasr[0];
        float fg = acc[1][i] + biasr[1];
        float gg = acc[2][i] + biasr[2];
        float og = acc[3][i] + biasr[3];
        float cn = sigm(fg)*c[i] + sigm(ig)*tanh_(gg);
        float hn = sigm(og)*tanh_(cn);
        bool mk = (tg < lens[i]);
        c[i] = mk ? cn : c[i];
        h[i] = mk ? hn : h[i];
        unsigned short hb = f2bf(h[i]);
        Albuf[wb][s_*512 + q_*128 + (quad*4+i)*8 + ko] = hb;
        if (HM == 1) hp[(quad*4+i)*8] = hb;
      }
      if (w == 2){
        *(u32x4*)&Albuf[wb][4096 + l*8] = xr0;
        xr0 = xr1;
        int t3 = d ? (tg-3) : (tg+3);
        t3 = t3 < 0 ? 0 : (t3 > TT-1 ? TT-1 : t3);
        xr1 = *(const u32x4*)&Xg[(size_t)t3*512 + l*8];
      }
    }
    __syncthreads();
    p ^= 1;
  }
}

// ---------------------------------------------------------------------------
// Phase 1b: y projection as a batched MFMA GEMM over h_all. (r7 proven)
// ---------------------------------------------------------------------------
__global__ __launch_bounds__(256) void y_proj(
    const unsigned short* __restrict__ h_all,
    const unsigned short* __restrict__ Wpk,
    unsigned short* __restrict__ y_ws)
{
  int gidx = blockIdx.x*4 + (threadIdx.x>>6);
  int l = threadIdx.x & 63;
  int d = gidx >> 13;
  int quad = l>>4, cr = l&15;
  const s16x8* hp = (const s16x8*)(h_all + (size_t)gidx*4096);
  const s16x8* BP = (const s16x8*)Wpk;
  int b0 = (d*66 + 64)*9*64;
  int b1 = (d*66 + 65)*9*64;
  f32x4 y0, y1;
  s16x8 a_c = hp[l], a_n;
  s16x8 w0 = BP[b0 + l], w1 = BP[b1 + l], w0n, w1n;
  #pragma unroll
  for (int s=0;s<8;s++){
    if (s < 7){
      a_n = hp[(s+1)*64 + l];
      w0n = BP[b0 + (s+1)*64 + l];
      w1n = BP[b1 + (s+1)*64 + l];
    }
    if (s == 0){
      f32x4 zz = {0.f,0.f,0.f,0.f};
      y0 = __builtin_amdgcn_mfma_f32_16x16x32_bf16(a_c, w0, zz, 0,0,0);
      y1 = __builtin_amdgcn_mfma_f32_16x16x32_bf16(a_c, w1, zz, 0,0,0);
    } else {
      y0 = __builtin_amdgcn_mfma_f32_16x16x32_bf16(a_c, w0, y0, 0,0,0);
      y1 = __builtin_amdgcn_mfma_f32_16x16x32_bf16(a_c, w1, y1, 0,0,0);
    }
    a_c = a_n; w0 = w0n; w1 = w1n;
  }
  unsigned short* yp = y_ws + (size_t)gidx*512;
  #pragma unroll
  for (int i=0;i<4;i++){
    yp[(quad*4+i)*32 + cr]      = f2bf(y0[i]);
    yp[(quad*4+i)*32 + 16 + cr] = f2bf(y1[i]);
  }
}

// ---------------------------------------------------------------------------
// Phase 2: per-batch head: tanh(y_f+y_b+addr_feat) . comb_W, masked log_softmax.
// ---------------------------------------------------------------------------
__global__ __launch_bounds__(256) void combine_kernel(
    const unsigned short* __restrict__ y_ws,
    const float* __restrict__ addr, const int* __restrict__ addr_type,
    const float* __restrict__ poi, const float* __restrict__ addrW,
    const float* __restrict__ addrB, const float* __restrict__ combW,
    const int* __restrict__ dlen, float* __restrict__ out)
{
  int b = blockIdx.x, tid = threadIdx.x;
  int grp = b >> 4, row = b & 15;
  __shared__ float af[32], cw[32], red[256];
  if (tid < 32){
    float s = addrB[tid] + addrW[tid*4]*addr[b];
    int at = addr_type[b];
    #pragma unroll
    for (int e=0;e<3;e++) s += addrW[tid*4+1+e]*poi[at*3+e];
    af[tid] = s;
    cw[tid] = combW[tid];
  }
  __syncthreads();
  int len = dlen[b];
  float sv[4];
  float lmax = -3.0e38f;
  #pragma unroll
  for (int kk=0;kk<4;kk++){
    int t = tid + kk*256;
    const u32x4* pf = (const u32x4*)(y_ws + ((((size_t)grp)*TT + t)*16 + row)*32);
    const u32x4* pb = (const u32x4*)(y_ws + ((((size_t)(8+grp))*TT + t)*16 + row)*32);
    float s = 0.f;
    #pragma unroll
    for (int ck=0; ck<4; ck++){
      u32x4 uf = pf[ck], ub = pb[ck];
      #pragma unroll
      for (int e=0;e<4;e++){
        int j = ck*8 + e*2;
        float v0 = bflo(uf[e]) + bflo(ub[e]) + af[j];
        float v1 = bfhi(uf[e]) + bfhi(ub[e]) + af[j+1];
        s += cw[j]*tanh_(v0) + cw[j+1]*tanh_(v1);
      }
    }
    sv[kk] = s;
    if (t < len) lmax = fmaxf(lmax, s);
  }
  red[tid] = lmax; __syncthreads();
  for (int off=128; off>0; off>>=1){
    if (tid < off) red[tid] = fmaxf(red[tid], red[tid+off]);
    __syncthreads();
  }
  float gmax = red[0];
  __syncthreads();
  float ls = 0.f;
  #pragma unroll
  for (int kk=0;kk<4;kk++){
    int t = tid + kk*256;
    if (t < len) ls += ex2(LOG2E*(sv[kk]-gmax));
  }
  red[tid] = ls; __syncthreads();
  for (int off=128; off>0; off>>=1){
    if (tid < off) red[tid] += red[tid+off];
    __syncthreads();
  }
  float lnz = __builtin_amdgcn_logf(red[0]) * (1.f/LOG2E);
  #pragma unroll
  for (int kk=0;kk<4;kk++){
    int t = tid + kk*256;
    out[(size_t)b*TT + t] = (t < len) ? (sv[kk]-gmax-lnz) : 0.f;
  }
}

// ---------------------------------------------------------------------------
extern "C" void kernel_launch(void* const* d_in, const int* in_sizes, int n_in,
                              void* d_out, int out_size, void* d_ws, size_t ws_size,
                              hipStream_t stream)
{
  const float* addr  = (const float*)d_in[0];
  const int*   atyp  = (const int*)d_in[1];
  const float* loc   = (const float*)d_in[2];
  const float* tdsq  = (const float*)d_in[3];
  const int*   dlen  = (const int*)d_in[4];
  const float* poi   = (const float*)d_in[5];
  const float* timeW = (const float*)d_in[6];
  const float* timeB = (const float*)d_in[7];
  const float* addrW = (const float*)d_in[8];
  const float* addrB = (const float*)d_in[9];
  const float* WihF  = (const float*)d_in[10];
  const float* WhhF  = (const float*)d_in[11];
  const float* bF    = (const float*)d_in[12];
  const float* WihB  = (const float*)d_in[13];
  const float* WhhB  = (const float*)d_in[14];
  const float* bB    = (const float*)d_in[15];
  const float* outW  = (const float*)d_in[16];
  const float* combW = (const float*)d_in[17];

  unsigned short* Wpk  = (unsigned short*)d_ws;                       // 1,216,512 B
  unsigned short* y_ws = (unsigned short*)((char*)d_ws + 1216512);    // 16,777,216 B
  unsigned short* Xpk  = (unsigned short*)((char*)d_ws + 17993728);   //  8,388,608 B
  unsigned short* h_all= (unsigned short*)((char*)d_ws + 26382336);   // 134,217,728 B
  int*            flg  = (int*)((char*)d_ws + 160600064);             //        256 B
  float* outp = (float*)d_out;

  const size_t WS_HM1   = 160600064ull;
  const size_t WS_SPLIT = 160600320ull;

  pack_weights<<<297, 256, 0, stream>>>(WhhF, WihF, WhhB, WihB, outW, Wpk);
  pack_x<<<8192, 64, 0, stream>>>(loc, tdsq, timeW, timeB, Xpk);
  if (ws_size >= WS_SPLIT){
    zero_flags<<<1, 64, 0, stream>>>(flg);
    lstm_split<<<32, 512, 0, stream>>>(dlen, bF, bB, Wpk, Xpk, h_all, flg);
    y_proj<<<4096, 256, 0, stream>>>(h_all, Wpk, y_ws);
  } else if (ws_size >= WS_HM1){
    lstm_kernel<1><<<16, 1024, 0, stream>>>(dlen, bF, bB, Wpk, Xpk, y_ws, h_all);
    y_proj<<<4096, 256, 0, stream>>>(h_all, Wpk, y_ws);
  } else {
    lstm_kernel<0><<<16, 1024, 0, stream>>>(dlen, bF, bB, Wpk, Xpk, y_ws, h_all);
  }
  combine_kernel<<<128, 256, 0, stream>>>(y_ws, addr, atyp, poi, addrW, addrB, combW, dlen, outp);
}

// Round 14
// 2064.219 us; speedup vs baseline: 1.0754x; 1.0754x over previous
//
#include <hip/hip_runtime.h>

#define TT 1024
#define LOG2E 1.44269504088896340736f

typedef __attribute__((ext_vector_type(8))) short s16x8;
typedef __attribute__((ext_vector_type(4))) float f32x4;
typedef __attribute__((ext_vector_type(4))) unsigned int u32x4;
typedef __attribute__((ext_vector_type(2))) unsigned int u32x2;

__device__ __forceinline__ float ex2(float x){ return __builtin_amdgcn_exp2f(x); }
__device__ __forceinline__ float rcp_(float x){ return __builtin_amdgcn_rcpf(x); }
__device__ __forceinline__ float sigm(float x){ return rcp_(1.f + ex2(-LOG2E*x)); }
__device__ __forceinline__ float tanh_(float x){
  float t = ex2(2.f*LOG2E*x);
  return 1.f - 2.f*rcp_(t + 1.f);
}
__device__ __forceinline__ unsigned short f2bf(float f){
  unsigned int u = __float_as_uint(f);
  u += 0x7fffu + ((u>>16)&1u);
  return (unsigned short)(u>>16);
}
__device__ __forceinline__ float bflo(unsigned int u){ return __uint_as_float(u << 16); }
__device__ __forceinline__ float bfhi(unsigned int u){ return __uint_as_float(u & 0xffff0000u); }

// ---------------------------------------------------------------------------
// Phase 0a: pack weights into MFMA B-fragment layout, bf16. (round-0 proven)
// Wpk layout: [d(2)][tau(66)][s(9)][lane(64)][8 bf16]
// ---------------------------------------------------------------------------
__global__ __launch_bounds__(256) void pack_weights(
    const float* __restrict__ WhhF, const float* __restrict__ WihF,
    const float* __restrict__ WhhB, const float* __restrict__ WihB,
    const float* __restrict__ outW, unsigned short* __restrict__ Wpk)
{
  int gid = blockIdx.x*256 + threadIdx.x;
  const int TOT = 2*66*9*64;
  if (gid >= TOT) return;
  int l   = gid & 63;
  int s   = (gid>>6) % 9;
  int tau = ((gid>>6)/9) % 66;
  int d   = gid / (66*9*64);
  const float* Whh = d ? WhhB : WhhF;
  const float* Wih = d ? WihB : WihF;
  int kb = s*32 + (l>>4)*8;
  int cr = l & 15;
  unsigned short v[8];
  #pragma unroll
  for (int j=0;j<8;j++){
    int k = kb + j;
    float val = 0.f;
    if (tau < 64){
      int col = 256*(tau&3) + 16*(tau>>2) + cr;
      if (k < 256)      val = Whh[col*256 + k];
      else if (k < 275) val = Wih[col*19 + (k-256)];
    } else {
      int col = 16*(tau-64) + cr;
      if (k < 256)      val = outW[col*512 + d*256 + k];
    }
    v[j] = f2bf(val);
  }
  u32x4 pk;
  pk[0] = (unsigned)v[0] | ((unsigned)v[1]<<16);
  pk[1] = (unsigned)v[2] | ((unsigned)v[3]<<16);
  pk[2] = (unsigned)v[4] | ((unsigned)v[5]<<16);
  pk[3] = (unsigned)v[6] | ((unsigned)v[7]<<16);
  *(u32x4*)&Wpk[(size_t)gid*8] = pk;
}

// ---------------------------------------------------------------------------
// Phase 0b: precompute the slice-8 A-fragment (x + time embed). (r6 proven)
// ---------------------------------------------------------------------------
__global__ __launch_bounds__(64) void pack_x(
    const float* __restrict__ loc, const float* __restrict__ tds,
    const float* __restrict__ timeW, const float* __restrict__ timeB,
    unsigned short* __restrict__ Xpk)
{
  int bid = blockIdx.x;            // grp*TT + t
  int t   = bid & (TT-1);
  int grp = bid >> 10;
  int l = threadIdx.x;
  int b = l & 15;
  int khi = l >> 4;
  unsigned short v[8];
  #pragma unroll
  for (int j=0;j<8;j++){
    int k = khi*8 + j;
    float val = 0.f;
    if (k < 16){
      val = loc[(((size_t)(grp*16 + b))*TT + t)*16 + k];
    } else if (k < 19){
      int jj = k - 16;
      const float* pt = &tds[(((size_t)(grp*16 + b))*TT + t)*8];
      float td = timeB[jj];
      #pragma unroll
      for (int dd=0; dd<4; dd++) td += pt[dd]*timeW[jj*8+dd] + pt[4+dd]*timeW[jj*8+4+dd];
      val = td;
    }
    v[j] = f2bf(val);
  }
  u32x4 pk;
  pk[0] = (unsigned)v[0] | ((unsigned)v[1]<<16);
  pk[1] = (unsigned)v[2] | ((unsigned)v[3]<<16);
  pk[2] = (unsigned)v[4] | ((unsigned)v[5]<<16);
  pk[3] = (unsigned)v[6] | ((unsigned)v[7]<<16);
  *(u32x4*)&Xpk[(size_t)bid*512 + l*8] = pk;
}

__global__ void zero_flags(int* __restrict__ f){ f[threadIdx.x] = 0; }

// ---------------------------------------------------------------------------
// do_own<H>: 5 MFMA slices (own half h + x). do_par<H>: 4 partner slices.
// Compile-time weight indices (runtime-indexed reg arrays go to scratch).
// Summation order (own, x, partner) identical to round-8 do9.
// ---------------------------------------------------------------------------
template<int H>
__device__ __forceinline__ void do_own(
    const s16x8 (&wgt)[9][4],
    s16x8 a0, s16x8 a1, s16x8 a2, s16x8 a3, s16x8 ax,
    f32x4 (&acc)[4])
{
  constexpr int O = H ? 4 : 0;
  f32x4 zz = {0.f,0.f,0.f,0.f};
  #pragma unroll
  for (int g=0;g<4;g++) acc[g] = __builtin_amdgcn_mfma_f32_16x16x32_bf16(a0, wgt[O+0][g], zz,     0,0,0);
  #pragma unroll
  for (int g=0;g<4;g++) acc[g] = __builtin_amdgcn_mfma_f32_16x16x32_bf16(a1, wgt[O+1][g], acc[g], 0,0,0);
  #pragma unroll
  for (int g=0;g<4;g++) acc[g] = __builtin_amdgcn_mfma_f32_16x16x32_bf16(a2, wgt[O+2][g], acc[g], 0,0,0);
  #pragma unroll
  for (int g=0;g<4;g++) acc[g] = __builtin_amdgcn_mfma_f32_16x16x32_bf16(a3, wgt[O+3][g], acc[g], 0,0,0);
  #pragma unroll
  for (int g=0;g<4;g++) acc[g] = __builtin_amdgcn_mfma_f32_16x16x32_bf16(ax, wgt[8][g],   acc[g], 0,0,0);
}

template<int H>
__device__ __forceinline__ void do_par(
    const s16x8 (&wgt)[9][4],
    s16x8 p0, s16x8 p1, s16x8 p2, s16x8 p3,
    f32x4 (&acc)[4])
{
  constexpr int P = H ? 0 : 4;
  #pragma unroll
  for (int g=0;g<4;g++) acc[g] = __builtin_amdgcn_mfma_f32_16x16x32_bf16(p0, wgt[P+0][g], acc[g], 0,0,0);
  #pragma unroll
  for (int g=0;g<4;g++) acc[g] = __builtin_amdgcn_mfma_f32_16x16x32_bf16(p1, wgt[P+1][g], acc[g], 0,0,0);
  #pragma unroll
  for (int g=0;g<4;g++) acc[g] = __builtin_amdgcn_mfma_f32_16x16x32_bf16(p2, wgt[P+2][g], acc[g], 0,0,0);
  #pragma unroll
  for (int g=0;g<4;g++) acc[g] = __builtin_amdgcn_mfma_f32_16x16x32_bf16(p3, wgt[P+3][g], acc[g], 0,0,0);
}

// ---------------------------------------------------------------------------
// Phase 1 (primary): hidden-split LSTM. 32 blocks x 512 threads (8 waves).
// Round-8 structure + CACHE-BYPASS exchange (fix for r8's per-step L2
// writeback/invalidate, which showed as FETCH_SIZE 9->45MB and ate the win):
//   - h_all stores:   sc0 sc1 (system relaxed atomic ushort) -> LLC, L2 clean
//   - partner reads:  raw global_load_dwordx4 sc0 sc1 -> LLC, NO threadfence
//   - flag store:     raw sc0 sc1 store after __syncthreads (its vmcnt(0)
//                     drain orders the sc1 data stores) -> no wbl2, no inv
// Schedule: spin -> issue partner loads -> own/x MFMAs (hide LLC latency)
//   -> asm vmcnt(0) tied to p0..p3 (+sched_barrier, rule #18) -> partner MFMAs.
// This is the round-9 kernel VERBATIM (verified pass, 2071us total): the
// r10/r12/r13 protocol variants all failed the harness; per pre-commitment
// the session lands on the best verified configuration.
// ---------------------------------------------------------------------------
__global__ __launch_bounds__(512, 2) __attribute__((amdgpu_waves_per_eu(2, 2)))
void lstm_split(
    const int* __restrict__ dlen,
    const float* __restrict__ bF, const float* __restrict__ bB,
    const unsigned short* __restrict__ Wpk,
    const unsigned short* __restrict__ Xpk,
    unsigned short* __restrict__ h_all,
    int* __restrict__ flags)
{
  __shared__ alignas(16) unsigned short Albuf[2][4608];
  int tid = threadIdx.x;
  int w = tid >> 6, l = tid & 63;          // w in 0..7
  int bid = blockIdx.x;
  int d = bid >> 4, grp = (bid >> 1) & 7, half = bid & 1;
  int quad = l >> 4, cr = l & 15;
  int W = half*8 + w;                      // absolute unit-block 0..15

  { unsigned int* az = (unsigned int*)&Albuf[0][0];
    for (int i = tid; i < 4608; i += 512) az[i] = 0u; }

  int lens[4];
  #pragma unroll
  for (int i=0;i<4;i++) lens[i] = dlen[grp*16 + quad*4 + i];
  int maxlen = dlen[grp*16];               // lengths sorted descending

  const float* bias = d ? bB : bF;
  float biasr[4];
  #pragma unroll
  for (int g=0;g<4;g++) biasr[g] = bias[256*g + 16*W + cr];

  const s16x8* BP = (const s16x8*)Wpk;
  int btile = (d*66 + 4*W)*9*64;

  // ALL weights resident: 9 slices x 4 gates, loaded once, pinned.
  s16x8 wgt[9][4];
  #pragma unroll
  for (int s=0;s<9;s++){
    #pragma unroll
    for (int g=0;g<4;g++){
      wgt[s][g] = BP[btile + (g*9+s)*64 + l];
      asm volatile("" : "+v"(wgt[s][g]));
    }
  }

  const unsigned short* Xg = Xpk + (size_t)grp*TT*512;
  int pairbase = (d*8 + grp)*2;
  int* myf = &flags[pairbase + half];
  int* prf = &flags[pairbase + (half^1)];

  float c[4], h[4];
  #pragma unroll
  for (int i=0;i<4;i++){ c[i]=0.f; h[i]=0.f; }

  __syncthreads();   // zero done

  // x shift-register prologue (wave 2), r6-proven
  u32x4 xr0 = {0,0,0,0}, xr1 = {0,0,0,0};
  if (w == 2){
    int tt0 = d ? (maxlen-1) : 0;
    int tt1 = d ? (maxlen-2) : 1;
    int tt2 = d ? (maxlen-3) : 2;
    tt1 = tt1 < 0 ? 0 : (tt1 > TT-1 ? TT-1 : tt1);
    tt2 = tt2 < 0 ? 0 : (tt2 > TT-1 ? TT-1 : tt2);
    u32x4 x0 = *(const u32x4*)&Xg[(size_t)tt0*512 + l*8];
    xr0 = *(const u32x4*)&Xg[(size_t)tt1*512 + l*8];
    xr1 = *(const u32x4*)&Xg[(size_t)tt2*512 + l*8];
    *(u32x4*)&Albuf[0][4096 + l*8] = x0;
  }
  __syncthreads();

  int ob = half ? 4 : 0;                   // own slice base
  int pb = half ? 0 : 4;                   // partner slice base

  int p = 0;
  for (int vs = 0; vs < maxlen; vs++){
    int tg = d ? (maxlen-1-vs) : vs;
    const s16x8* ap = (const s16x8*)&Albuf[p][0];

    // own A-frags (LDS)
    s16x8 a0 = ap[(ob+0)*64 + l];
    s16x8 a1 = ap[(ob+1)*64 + l];
    s16x8 a2 = ap[(ob+2)*64 + l];
    s16x8 a3 = ap[(ob+3)*64 + l];
    s16x8 ax = ap[512 + l];                // slice 8 (x)

    // spin (usually one LLC read), then ISSUE partner sc1 loads (no wait yet)
    s16x8 p0 = {0,0,0,0,0,0,0,0};
    s16x8 p1 = p0, p2 = p0, p3 = p0;
    if (vs > 0){
      while (__hip_atomic_load(prf, __ATOMIC_RELAXED, __HIP_MEMORY_SCOPE_SYSTEM) < vs)
        __builtin_amdgcn_s_sleep(1);
      int tprev = d ? (tg+1) : (tg-1);
      const unsigned short* pt = h_all + ((size_t)((d*8+grp)*TT + tprev))*4096;
      asm volatile("global_load_dwordx4 %0, %1, off sc0 sc1"
                   : "=v"(p0) : "v"(&pt[(pb+0)*512 + l*8]) : "memory");
      asm volatile("global_load_dwordx4 %0, %1, off sc0 sc1"
                   : "=v"(p1) : "v"(&pt[(pb+1)*512 + l*8]) : "memory");
      asm volatile("global_load_dwordx4 %0, %1, off sc0 sc1"
                   : "=v"(p2) : "v"(&pt[(pb+2)*512 + l*8]) : "memory");
      asm volatile("global_load_dwordx4 %0, %1, off sc0 sc1"
                   : "=v"(p3) : "v"(&pt[(pb+3)*512 + l*8]) : "memory");
    }

    f32x4 acc[4];
    if (half == 0) do_own<0>(wgt, a0,a1,a2,a3,ax, acc);
    else           do_own<1>(wgt, a0,a1,a2,a3,ax, acc);

    // wait the partner loads; tie p0..p3 so MFMAs can't hoist past (rule #18)
    asm volatile("s_waitcnt vmcnt(0)"
                 : "+v"(p0), "+v"(p1), "+v"(p2), "+v"(p3) :: "memory");
    __builtin_amdgcn_sched_barrier(0);

    if (half == 0) do_par<0>(wgt, p0,p1,p2,p3, acc);
    else           do_par<1>(wgt, p0,p1,p2,p3, acc);

    int wb = p ^ 1;
    int kh = 16*W + cr;
    int s_ = kh >> 5, q_ = (kh>>3)&3, ko = kh & 7;
    unsigned short* hp = h_all + ((size_t)((d*8+grp)*TT + tg))*4096 + s_*512 + q_*128 + ko;
    #pragma unroll
    for (int i=0;i<4;i++){
      float ig = acc[0][i] + biasr[0];
      float fg = acc[1][i] + biasr[1];
      float gg = acc[2][i] + biasr[2];
      float og = acc[3][i] + biasr[3];
      float cn = sigm(fg)*c[i] + sigm(ig)*tanh_(gg);
      float hn = sigm(og)*tanh_(cn);
      bool mk = (tg < lens[i]);
      c[i] = mk ? cn : c[i];
      h[i] = mk ? hn : h[i];
      unsigned short hb = f2bf(h[i]);
      Albuf[wb][s_*512 + q_*128 + (quad*4+i)*8 + ko] = hb;
      // write-through to LLC (L2 stays clean -> no wbl2/inv ever needed)
      __hip_atomic_store(&hp[(quad*4+i)*8], hb, __ATOMIC_RELAXED,
                         __HIP_MEMORY_SCOPE_SYSTEM);
    }
    // x(t_next) from the 2-step shift register; issue t+3 load last
    if (w == 2){
      *(u32x4*)&Albuf[wb][4096 + l*8] = xr0;
      xr0 = xr1;
      int t3 = d ? (tg-3) : (tg+3);
      t3 = t3 < 0 ? 0 : (t3 > TT-1 ? TT-1 : t3);
      xr1 = *(const u32x4*)&Xg[(size_t)t3*512 + l*8];
    }
    __syncthreads();   // vmcnt(0) per wave: all sc1 h stores are LLC-visible
    if (tid == 0){
      int fv = vs + 1;
      asm volatile("global_store_dword %0, %1, off sc0 sc1"
                   :: "v"(myf), "v"(fv) : "memory");
    }
    p ^= 1;
  }
}

// ---------------------------------------------------------------------------
// Phase 1 (fallback, r7-verified): 16-block persistent LSTM, template HM.
// ---------------------------------------------------------------------------
template<int HM>
__global__ __launch_bounds__(1024) void lstm_kernel(
    const int* __restrict__ dlen,
    const float* __restrict__ bF, const float* __restrict__ bB,
    const unsigned short* __restrict__ Wpk,
    const unsigned short* __restrict__ Xpk,
    unsigned short* __restrict__ y_ws,
    unsigned short* __restrict__ h_all)
{
  __shared__ alignas(16) unsigned short Albuf[2][4608];
  int tid = threadIdx.x;
  int w = tid >> 6, l = tid & 63;
  int bid = blockIdx.x;
  int d = bid >> 3, grp = bid & 7;
  int quad = l >> 4, cr = l & 15;

  { unsigned int* az = (unsigned int*)&Albuf[0][0];
    for (int i = tid; i < 4608; i += 1024) az[i] = 0u; }

  int lens[4];
  #pragma unroll
  for (int i=0;i<4;i++) lens[i] = dlen[grp*16 + quad*4 + i];
  int maxlen = dlen[grp*16];

  const float* bias = d ? bB : bF;
  float biasr[4];
  #pragma unroll
  for (int g=0;g<4;g++) biasr[g] = bias[256*g + 16*w + cr];

  const s16x8* BP = (const s16x8*)Wpk;
  int btile  = (d*66 + 4*w)*9*64;
  int bytile = (d*66 + 64 + w)*9*64;
  bool has_y = (HM == 0) && (w < 2);

  const unsigned short* Xg = Xpk + (size_t)grp*TT*512;

  float c[4], h[4];
  #pragma unroll
  for (int i=0;i<4;i++){ c[i]=0.f; h[i]=0.f; }

  __syncthreads();

  u32x4 xr0 = {0,0,0,0}, xr1 = {0,0,0,0};
  if (w == 2){
    int tt0 = d ? (maxlen-1) : 0;
    int tt1 = d ? (maxlen-2) : 1;
    int tt2 = d ? (maxlen-3) : 2;
    tt1 = tt1 < 0 ? 0 : (tt1 > TT-1 ? TT-1 : tt1);
    tt2 = tt2 < 0 ? 0 : (tt2 > TT-1 ? TT-1 : tt2);
    u32x4 x0 = *(const u32x4*)&Xg[(size_t)tt0*512 + l*8];
    xr0 = *(const u32x4*)&Xg[(size_t)tt1*512 + l*8];
    xr1 = *(const u32x4*)&Xg[(size_t)tt2*512 + l*8];
    *(u32x4*)&Albuf[0][4096 + l*8] = x0;
  }
  __syncthreads();

  int p = 0;
  for (int vs = 0; vs <= maxlen; vs++){
    int tg = d ? (maxlen-1-vs) : vs;
    int ty = d ? (maxlen-vs)   : (vs-1);
    bool do_g = (vs < maxlen);

    const s16x8* ap = (const s16x8*)&Albuf[p][0];

    if (has_y && vs > 0){
      f32x4 yacc;
      s16x8 ya  = ap[l], yan;
      s16x8 yb0 = BP[bytile + l], ybn;
      #pragma unroll
      for (int s=0;s<9;s++){
        if (s < 8){
          yan = ap[(s+1)*64 + l];
          ybn = BP[bytile + (s+1)*64 + l];
        }
        if (s == 0){
          f32x4 zz = {0.f,0.f,0.f,0.f};
          yacc = __builtin_amdgcn_mfma_f32_16x16x32_bf16(ya, yb0, zz, 0,0,0);
        } else {
          yacc = __builtin_amdgcn_mfma_f32_16x16x32_bf16(ya, yb0, yacc, 0,0,0);
        }
        ya = yan; yb0 = ybn;
      }
      size_t ybase = ((((size_t)d*8 + grp)*TT + (size_t)ty)*16)*32;
      #pragma unroll
      for (int i=0;i<4;i++)
        y_ws[ybase + (size_t)(quad*4+i)*32 + 16*w + cr] = f2bf(yacc[i]);
    }

    if (do_g){
      f32x4 acc[4];
      s16x8 bb[2][4];
      #pragma unroll
      for (int g=0;g<4;g++) bb[0][g] = BP[btile + (g*9)*64 + l];
      #pragma unroll
      for (int g=0;g<4;g++) bb[1][g] = BP[btile + (g*9+1)*64 + l];
      s16x8 a_c = ap[l], a_n;
      #pragma unroll
      for (int s=0;s<9;s++){
        const int cu = s & 1;
        if (s < 8) a_n = ap[(s+1)*64 + l];
        #pragma unroll
        for (int g=0;g<4;g++){
          if (s == 0){
            f32x4 zz = {0.f,0.f,0.f,0.f};
            acc[g] = __builtin_amdgcn_mfma_f32_16x16x32_bf16(a_c, bb[cu][g], zz, 0,0,0);
          } else {
            acc[g] = __builtin_amdgcn_mfma_f32_16x16x32_bf16(a_c, bb[cu][g], acc[g], 0,0,0);
          }
        }
        if (s < 7){
          #pragma unroll
          for (int g=0;g<4;g++)
            bb[cu][g] = BP[btile + (g*9 + s+2)*64 + l];
        }
        a_c = a_n;
      }

      int wb = p ^ 1;
      int kh = 16*w + cr;
      int s_ = kh >> 5, q_ = (kh>>3)&3, ko = kh & 7;
      unsigned short* hp = (HM == 1)
        ? (h_all + ((size_t)((d*8+grp)*TT + tg))*4096 + s_*512 + q_*128 + ko)
        : nullptr;
      #pragma unroll
      for (int i=0;i<4;i++){
        float ig = acc[0][i] + biasr[0];
        float fg = acc[1][i] + biasr[1];
        float gg = acc[2][i] + biasr[2];
        float og = acc[3][i] + biasr[3];
        float cn = sigm(fg)*c[i] + sigm(ig)*tanh_(gg);
        float hn = sigm(og)*tanh_(cn);
        bool mk = (tg < lens[i]);
        c[i] = mk ? cn : c[i];
        h[i] = mk ? hn : h[i];
        unsigned short hb = f2bf(h[i]);
        Albuf[wb][s_*512 + q_*128 + (quad*4+i)*8 + ko] = hb;
        if (HM == 1) hp[(quad*4+i)*8] = hb;
      }
      if (w == 2){
        *(u32x4*)&Albuf[wb][4096 + l*8] = xr0;
        xr0 = xr1;
        int t3 = d ? (tg-3) : (tg+3);
        t3 = t3 < 0 ? 0 : (t3 > TT-1 ? TT-1 : t3);
        xr1 = *(const u32x4*)&Xg[(size_t)t3*512 + l*8];
      }
    }
    __syncthreads();
    p ^= 1;
  }
}

// ---------------------------------------------------------------------------
// Phase 1b: y projection as a batched MFMA GEMM over h_all. (r7 proven)
// ---------------------------------------------------------------------------
__global__ __launch_bounds__(256) void y_proj(
    const unsigned short* __restrict__ h_all,
    const unsigned short* __restrict__ Wpk,
    unsigned short* __restrict__ y_ws)
{
  int gidx = blockIdx.x*4 + (threadIdx.x>>6);
  int l = threadIdx.x & 63;
  int d = gidx >> 13;
  int quad = l>>4, cr = l&15;
  const s16x8* hp = (const s16x8*)(h_all + (size_t)gidx*4096);
  const s16x8* BP = (const s16x8*)Wpk;
  int b0 = (d*66 + 64)*9*64;
  int b1 = (d*66 + 65)*9*64;
  f32x4 y0, y1;
  s16x8 a_c = hp[l], a_n;
  s16x8 w0 = BP[b0 + l], w1 = BP[b1 + l], w0n, w1n;
  #pragma unroll
  for (int s=0;s<8;s++){
    if (s < 7){
      a_n = hp[(s+1)*64 + l];
      w0n = BP[b0 + (s+1)*64 + l];
      w1n = BP[b1 + (s+1)*64 + l];
    }
    if (s == 0){
      f32x4 zz = {0.f,0.f,0.f,0.f};
      y0 = __builtin_amdgcn_mfma_f32_16x16x32_bf16(a_c, w0, zz, 0,0,0);
      y1 = __builtin_amdgcn_mfma_f32_16x16x32_bf16(a_c, w1, zz, 0,0,0);
    } else {
      y0 = __builtin_amdgcn_mfma_f32_16x16x32_bf16(a_c, w0, y0, 0,0,0);
      y1 = __builtin_amdgcn_mfma_f32_16x16x32_bf16(a_c, w1, y1, 0,0,0);
    }
    a_c = a_n; w0 = w0n; w1 = w1n;
  }
  unsigned short* yp = y_ws + (size_t)gidx*512;
  #pragma unroll
  for (int i=0;i<4;i++){
    yp[(quad*4+i)*32 + cr]      = f2bf(y0[i]);
    yp[(quad*4+i)*32 + 16 + cr] = f2bf(y1[i]);
  }
}

// ---------------------------------------------------------------------------
// Phase 2: per-batch head: tanh(y_f+y_b+addr_feat) . comb_W, masked log_softmax.
// ---------------------------------------------------------------------------
__global__ __launch_bounds__(256) void combine_kernel(
    const unsigned short* __restrict__ y_ws,
    const float* __restrict__ addr, const int* __restrict__ addr_type,
    const float* __restrict__ poi, const float* __restrict__ addrW,
    const float* __restrict__ addrB, const float* __restrict__ combW,
    const int* __restrict__ dlen, float* __restrict__ out)
{
  int b = blockIdx.x, tid = threadIdx.x;
  int grp = b >> 4, row = b & 15;
  __shared__ float af[32], cw[32], red[256];
  if (tid < 32){
    float s = addrB[tid] + addrW[tid*4]*addr[b];
    int at = addr_type[b];
    #pragma unroll
    for (int e=0;e<3;e++) s += addrW[tid*4+1+e]*poi[at*3+e];
    af[tid] = s;
    cw[tid] = combW[tid];
  }
  __syncthreads();
  int len = dlen[b];
  float sv[4];
  float lmax = -3.0e38f;
  #pragma unroll
  for (int kk=0;kk<4;kk++){
    int t = tid + kk*256;
    const u32x4* pf = (const u32x4*)(y_ws + ((((size_t)grp)*TT + t)*16 + row)*32);
    const u32x4* pb = (const u32x4*)(y_ws + ((((size_t)(8+grp))*TT + t)*16 + row)*32);
    float s = 0.f;
    #pragma unroll
    for (int ck=0; ck<4; ck++){
      u32x4 uf = pf[ck], ub = pb[ck];
      #pragma unroll
      for (int e=0;e<4;e++){
        int j = ck*8 + e*2;
        float v0 = bflo(uf[e]) + bflo(ub[e]) + af[j];
        float v1 = bfhi(uf[e]) + bfhi(ub[e]) + af[j+1];
        s += cw[j]*tanh_(v0) + cw[j+1]*tanh_(v1);
      }
    }
    sv[kk] = s;
    if (t < len) lmax = fmaxf(lmax, s);
  }
  red[tid] = lmax; __syncthreads();
  for (int off=128; off>0; off>>=1){
    if (tid < off) red[tid] = fmaxf(red[tid], red[tid+off]);
    __syncthreads();
  }
  float gmax = red[0];
  __syncthreads();
  float ls = 0.f;
  #pragma unroll
  for (int kk=0;kk<4;kk++){
    int t = tid + kk*256;
    if (t < len) ls += ex2(LOG2E*(sv[kk]-gmax));
  }
  red[tid] = ls; __syncthreads();
  for (int off=128; off>0; off>>=1){
    if (tid < off) red[tid] += red[tid+off];
    __syncthreads();
  }
  float lnz = __builtin_amdgcn_logf(red[0]) * (1.f/LOG2E);
  #pragma unroll
  for (int kk=0;kk<4;kk++){
    int t = tid + kk*256;
    out[(size_t)b*TT + t] = (t < len) ? (sv[kk]-gmax-lnz) : 0.f;
  }
}

// ---------------------------------------------------------------------------
extern "C" void kernel_launch(void* const* d_in, const int* in_sizes, int n_in,
                              void* d_out, int out_size, void* d_ws, size_t ws_size,
                              hipStream_t stream)
{
  const float* addr  = (const float*)d_in[0];
  const int*   atyp  = (const int*)d_in[1];
  const float* loc   = (const float*)d_in[2];
  const float* tdsq  = (const float*)d_in[3];
  const int*   dlen  = (const int*)d_in[4];
  const float* poi   = (const float*)d_in[5];
  const float* timeW = (const float*)d_in[6];
  const float* timeB = (const float*)d_in[7];
  const float* addrW = (const float*)d_in[8];
  const float* addrB = (const float*)d_in[9];
  const float* WihF  = (const float*)d_in[10];
  const float* WhhF  = (const float*)d_in[11];
  const float* bF    = (const float*)d_in[12];
  const float* WihB  = (const float*)d_in[13];
  const float* WhhB  = (const float*)d_in[14];
  const float* bB    = (const float*)d_in[15];
  const float* outW  = (const float*)d_in[16];
  const float* combW = (const float*)d_in[17];

  unsigned short* Wpk  = (unsigned short*)d_ws;                       // 1,216,512 B
  unsigned short* y_ws = (unsigned short*)((char*)d_ws + 1216512);    // 16,777,216 B
  unsigned short* Xpk  = (unsigned short*)((char*)d_ws + 17993728);   //  8,388,608 B
  unsigned short* h_all= (unsigned short*)((char*)d_ws + 26382336);   // 134,217,728 B
  int*            flg  = (int*)((char*)d_ws + 160600064);             //        256 B
  float* outp = (float*)d_out;

  const size_t WS_HM1   = 160600064ull;
  const size_t WS_SPLIT = 160600320ull;

  pack_weights<<<297, 256, 0, stream>>>(WhhF, WihF, WhhB, WihB, outW, Wpk);
  pack_x<<<8192, 64, 0, stream>>>(loc, tdsq, timeW, timeB, Xpk);
  if (ws_size >= WS_SPLIT){
    zero_flags<<<1, 64, 0, stream>>>(flg);
    lstm_split<<<32, 512, 0, stream>>>(dlen, bF, bB, Wpk, Xpk, h_all, flg);
    y_proj<<<4096, 256, 0, stream>>>(h_all, Wpk, y_ws);
  } else if (ws_size >= WS_HM1){
    lstm_kernel<1><<<16, 1024, 0, stream>>>(dlen, bF, bB, Wpk, Xpk, y_ws, h_all);
    y_proj<<<4096, 256, 0, stream>>>(h_all, Wpk, y_ws);
  } else {
    lstm_kernel<0><<<16, 1024, 0, stream>>>(dlen, bF, bB, Wpk, Xpk, y_ws, h_all);
  }
  combine_kernel<<<128, 256, 0, stream>>>(y_ws, addr, atyp, poi, addrW, addrB, combW, dlen, outp);
}